// Round 16
// baseline (295.627 us; speedup 1.0000x reference)
//
#include <hip/hip_runtime.h>

using u64 = unsigned long long;
typedef _Float16 f16;
using f16x8 = __attribute__((ext_vector_type(8))) _Float16;
using f16x4 = __attribute__((ext_vector_type(4))) _Float16;
using f32x4 = __attribute__((ext_vector_type(4))) float;

// ======================= Hilbert encode (Skilling) =======================
__device__ __forceinline__ int hilbert3(int X0, int X1, int X2) {
  #pragma unroll
  for (int Q = 256; Q > 1; Q >>= 1) {
    const int P = Q - 1;
    if (X0 & Q) X0 ^= P;
    int t1 = (X0 ^ X1) & P;
    if (X1 & Q) X0 ^= P; else { X0 ^= t1; X1 ^= t1; }
    int t2 = (X0 ^ X2) & P;
    if (X2 & Q) X0 ^= P; else { X0 ^= t2; X2 ^= t2; }
  }
  X1 ^= X0;
  X2 ^= X1;
  int t = 0;
  #pragma unroll
  for (int Q = 256; Q > 1; Q >>= 1) if (X2 & Q) t ^= (Q - 1);
  X0 ^= t; X1 ^= t; X2 ^= t;
  int code = 0;
  #pragma unroll
  for (int b = 8; b >= 0; b--)
    code = (code << 3) | (((X0 >> b) & 1) << 2) | (((X1 >> b) & 1) << 1) | ((X2 >> b) & 1);
  return code;
}

__device__ __forceinline__ void cswap(u64& a, u64& b, bool up) {
  if ((a > b) == up) { u64 t = a; a = b; b = t; }
}

// ======= fused: encode + 2048-tile local sort (sort blocks) | prep (tail) =====
__global__ __launch_bounds__(1024) void sort_tile0_prep(
    const int* __restrict__ vox, u64* __restrict__ keys, int n, int spanm1, int nbsort,
    const float* __restrict__ Wq1, const float* __restrict__ Wk1,
    const float* __restrict__ Wv1, const float* __restrict__ Wo1,
    const float* __restrict__ Wout1,
    const float* __restrict__ Wq2, const float* __restrict__ Wk2,
    const float* __restrict__ Wv2, const float* __restrict__ Wo2,
    const float* __restrict__ Wout2,
    f16* __restrict__ A1a, f16* __restrict__ A2a, f16* __restrict__ A3a,
    f16* __restrict__ A1b, f16* __restrict__ A2b, f16* __restrict__ A3b) {
  if ((int)blockIdx.x >= nbsort) {
    // ---- weight-folding tail blocks (16 x 1024 threads = 16384) ----
    const int idx = (blockIdx.x - nbsort) * 1024 + threadIdx.x;
    if (idx < 4096) {
      const int a = idx >> 6, b = idx & 63;
      float s1 = 0.f, s2 = 0.f;
      for (int c = 0; c < 64; c++) {
        s1 = fmaf(Wq1[b * 64 + c], Wk1[a * 64 + c], s1);
        s2 = fmaf(Wv1[b * 64 + c], Wo1[c * 64 + a], s2);
      }
      A1a[idx] = (f16)(s1 * 0.125f);
      A2a[idx] = (f16)s2;
    }
    if (idx < 8192) {
      const int o = idx >> 6, c = idx & 63;
      A3a[idx] = (f16)Wout1[c * 128 + o];
    }
    {
      const int a = idx >> 7, b = idx & 127;
      float s1 = 0.f, s2 = 0.f;
      for (int c = 0; c < 128; c++) {
        s1 = fmaf(Wq2[b * 128 + c], Wk2[a * 128 + c], s1);
        s2 = fmaf(Wv2[b * 128 + c], Wo2[c * 128 + a], s2);
      }
      A1b[idx] = (f16)(s1 * 0.08838834764831845f);
      A2b[idx] = (f16)s2;
      A3b[idx] = (f16)Wout2[b * 128 + a];
    }
    return;
  }
  __shared__ u64 s[2048];
  const int base = blockIdx.x * 2048;
  const int bl = base & spanm1;
  #pragma unroll
  for (int m = 0; m < 2; m++) {
    const int e = base + threadIdx.x + m * 1024;
    const int isrc = e & (n - 1);
    const int4 c = ((const int4*)vox)[isrc];
    const unsigned code = (e < n) ? (unsigned)hilbert3(c.y, c.z, c.w)
                                  : (unsigned)hilbert3(c.w, c.z, c.y);
    s[threadIdx.x + m * 1024] =
        ((u64)(unsigned)c.x << 45) | ((u64)code << 18) | (unsigned)isrc;
  }
  __syncthreads();
  for (int k = 2; k <= 2048; k <<= 1) {
    for (int j = k >> 1; j >= 1; j >>= 1) {
      const int p = threadIdx.x;
      const int i = ((p & ~(j - 1)) << 1) | (p & (j - 1));
      const bool up = (((bl + i) & k) == 0);
      u64 a = s[i], b = s[i | j];
      if ((a > b) == up) { s[i] = b; s[i | j] = a; }
      __syncthreads();
    }
  }
  keys[base + threadIdx.x]        = s[threadIdx.x];
  keys[base + threadIdx.x + 1024] = s[threadIdx.x + 1024];
}

template<int LEV>
__device__ __forceinline__ void gstepT(u64* __restrict__ keys, int t, int jlow,
                                       int k, int spanm1) {
  constexpr int S = 1 << LEV;
  const int i0 = ((t & ~(jlow - 1)) << LEV) | (t & (jlow - 1));
  const bool up = (((i0 & spanm1) & k) == 0);
  u64 x[S];
  #pragma unroll
  for (int m = 0; m < S; m++) x[m] = keys[i0 + (size_t)m * jlow];
  #pragma unroll
  for (int d = S >> 1; d >= 1; d >>= 1)
    #pragma unroll
    for (int m = 0; m < S; m++)
      if (!(m & d)) cswap(x[m], x[m | d], up);
  #pragma unroll
  for (int m = 0; m < S; m++) keys[i0 + (size_t)m * jlow] = x[m];
}

__global__ void bitonic_gN(u64* __restrict__ keys, int jlow, int lev, int k, int spanm1) {
  const int t = blockIdx.x * blockDim.x + threadIdx.x;
  switch (lev) {
    case 1: gstepT<1>(keys, t, jlow, k, spanm1); break;
    case 2: gstepT<2>(keys, t, jlow, k, spanm1); break;
    case 3: gstepT<3>(keys, t, jlow, k, spanm1); break;
    default: gstepT<4>(keys, t, jlow, k, spanm1); break;
  }
}

__global__ __launch_bounds__(1024) void merge_tile4(u64* __restrict__ keys, int k,
                                                    int spanm1) {
  __shared__ u64 s[4096];
  const int base = blockIdx.x * 4096;
  #pragma unroll
  for (int m = 0; m < 4; m++)
    s[threadIdx.x + m * 1024] = keys[base + threadIdx.x + m * 1024];
  __syncthreads();
  const bool up = (((base & spanm1) & k) == 0);
  for (int j = 2048; j >= 1; j >>= 1) {
    #pragma unroll
    for (int m = 0; m < 2; m++) {
      const int p = threadIdx.x + m * 1024;
      const int i = ((p & ~(j - 1)) << 1) | (p & (j - 1));
      u64 a = s[i], b = s[i | j];
      if ((a > b) == up) { s[i] = b; s[i | j] = a; }
    }
    __syncthreads();
  }
  #pragma unroll
  for (int m = 0; m < 4; m++)
    keys[base + threadIdx.x + m * 1024] = s[threadIdx.x + m * 1024];
}

// ==== FINAL merge: consumes sorted tile directly (keys never written back) ====
// ordering-1 blocks (base < n): ind1 + gathered pts1p.
// ordering-2 blocks: inv2 + out_pts/out_vox/out_nb.
__global__ __launch_bounds__(1024) void merge_final(
    const u64* __restrict__ keys, int k, int spanm1, int n, int B,
    const float* __restrict__ pts, const int* __restrict__ vox,
    const int* __restrict__ numbs,
    int* __restrict__ ind1, int* __restrict__ inv2, float* __restrict__ pts1p,
    float* __restrict__ out_pts, float* __restrict__ out_vox,
    float* __restrict__ out_nb) {
  __shared__ u64 s[4096];
  const int base = blockIdx.x * 4096;
  #pragma unroll
  for (int m = 0; m < 4; m++)
    s[threadIdx.x + m * 1024] = keys[base + threadIdx.x + m * 1024];
  __syncthreads();
  const bool up = (((base & spanm1) & k) == 0);
  for (int j = 2048; j >= 1; j >>= 1) {
    #pragma unroll
    for (int m = 0; m < 2; m++) {
      const int p = threadIdx.x + m * 1024;
      const int i = ((p & ~(j - 1)) << 1) | (p & (j - 1));
      u64 a = s[i], b = s[i | j];
      if ((a > b) == up) { s[i] = b; s[i | j] = a; }
    }
    __syncthreads();
  }
  if (base < n) {
    #pragma unroll
    for (int m = 0; m < 4; m++) {
      const int p = base + threadIdx.x + m * 1024;
      const int s1 = (int)(s[threadIdx.x + m * 1024] & 0x3FFFFULL);
      ind1[p] = s1;
      pts1p[p * 3 + 0] = pts[s1 * 3 + 0];
      pts1p[p * 3 + 1] = pts[s1 * 3 + 1];
      pts1p[p * 3 + 2] = pts[s1 * 3 + 2];
    }
  } else {
    #pragma unroll
    for (int m = 0; m < 4; m++) {
      const int p = base - n + threadIdx.x + m * 1024;
      const int s2 = (int)(s[threadIdx.x + m * 1024] & 0x3FFFFULL);
      inv2[s2] = p;
      out_pts[p * 3 + 0] = pts[s2 * 3 + 0];
      out_pts[p * 3 + 1] = pts[s2 * 3 + 1];
      out_pts[p * 3 + 2] = pts[s2 * 3 + 2];
      const int4 v = ((const int4*)vox)[s2];
      out_vox[p * 4 + 0] = (float)v.x;
      out_vox[p * 4 + 1] = (float)v.y;
      out_vox[p * 4 + 2] = (float)v.z;
      out_vox[p * 4 + 3] = (float)v.w;
      if (p < B) out_nb[p] = (float)numbs[p];
    }
  }
}

// ======================= MFMA attention block (8-wave fine partition) =========
__device__ __forceinline__ int swzb(int row) {
  return (((row & 7) ^ (((row >> 3) & 3) << 1)) << 4);
}

template<int M, int K, int AMODE>
__device__ __forceinline__ void stage8(const f16* __restrict__ Ag,
                                       const f16* __restrict__ lA,
                                       const f16* __restrict__ lB,
                                       int w, int lane,
                                       f32x4 (&acc)[(M / 16) * 4 / 8]) {
  constexpr int NPW = (M / 16) * 4 / 8;
  constexpr int KT = K / 32;
  const int lr = lane & 15, lk = lane >> 4;
  const int ct = (w * NPW) >> 2;
  const int qt0 = (w * NPW) & 3;
  const int c = ct * 16 + lr;
  f16x8 Af[KT];
  #pragma unroll
  for (int kt = 0; kt < KT; kt++) {
    const int k0 = kt * 32 + lk * 8;
    if (AMODE == 0) {
      Af[kt] = *(const f16x8*)(Ag + (size_t)c * K + k0);
    } else if (AMODE == 1) {
      Af[kt] = *(const f16x8*)((const char*)lA + (((c * K + k0) * 2) ^ swzb(c)));
    } else {
      f16x8 a;
      #pragma unroll
      for (int e = 0; e < 8; e++) {
        const int j = k0 + e;
        a[e] = *(const f16*)((const char*)lA + (((j * M + c) * 2) ^ swzb(j)));
      }
      Af[kt] = a;
    }
  }
  #pragma unroll
  for (int i = 0; i < NPW; i++) {
    const int q = lr + (qt0 + i) * 16;
    #pragma unroll
    for (int kt = 0; kt < KT; kt++) {
      const int k0 = kt * 32 + lk * 8;
      const f16x8 Bf = *(const f16x8*)((const char*)lB + (((q * K + k0) * 2) ^ swzb(q)));
      acc[i] = __builtin_amdgcn_mfma_f32_16x16x32_f16(Af[kt], Bf, acc[i], 0, 0, 0);
    }
  }
}

template<int RL, bool RELU>
__device__ __forceinline__ void store8(f16* __restrict__ dst, int ct, int qt,
                                       int lane, f32x4 v) {
  const int lr = lane & 15, lk = lane >> 4;
  const int q = lr + qt * 16;
  const int c0 = ct * 16 + lk * 4;
  f16x4 o;
  #pragma unroll
  for (int r = 0; r < 4; r++) {
    float x = v[r];
    if (RELU) x = fmaxf(x, 0.f);
    o[r] = (f16)x;
  }
  *(f16x4*)((char*)dst + (((q * RL + c0) * 2) ^ swzb(q))) = o;
}

// GATH: gather x rows via idx_x (else contiguous rows g*64+q).
// SCAT: scatter output rows to dmap[element] (else contiguous g*64+q).
template<int C, bool X16, bool OUT16, bool GATH, bool SCAT>
__global__ __launch_bounds__(512, 8) void block_mfma(
    const int* __restrict__ idx_x, const int* __restrict__ dmap,
    const float* __restrict__ ptsP, const void* __restrict__ xsrc,
    const float* __restrict__ Wpos, const float* __restrict__ bpos,
    const f16* __restrict__ A1, const f16* __restrict__ A2, const f16* __restrict__ A3,
    void* __restrict__ outp) {
  constexpr int NPWC = C / 32;             // tiles/wave for M=C stages
  extern __shared__ char smem[];
  f16* bufH = (f16*)smem;            // [64][C] h -> later o2r
  f16* bufT = bufH + 64 * C;         // [64][C] t1 -> later t2
  f16* scH  = bufT + 64 * C;         // [64][64] f16 scores -> attn
  int* sDest = (int*)(scH + 64 * 64);  // [64] scatter rows (SCAT only)

  const int g = blockIdx.x;
  const int t = threadIdx.x;
  const int lane = t & 63;
  const int w = t >> 6;
  const int lr = lane & 15, lk = lane >> 4;
  const int q8 = t >> 3, qq = t & 7;       // h-build / softmax: 8 threads per row

  // ---- h = x * ((p-mean)@Wpos + bpos) -> bufH ----
  {
    const int sx = GATH ? idx_x[g * 64 + q8] : (g * 64 + q8);
    if constexpr (SCAT) {
      if (qq == 0) sDest[q8] = dmap[sx];
    }
    float mx = ptsP[(g * 64 + lane) * 3 + 0];
    float my = ptsP[(g * 64 + lane) * 3 + 1];
    float mz = ptsP[(g * 64 + lane) * 3 + 2];
    #pragma unroll
    for (int o = 32; o > 0; o >>= 1) {
      mx += __shfl_xor(mx, o); my += __shfl_xor(my, o); mz += __shfl_xor(mz, o);
    }
    mx *= (1.f / 64.f); my *= (1.f / 64.f); mz *= (1.f / 64.f);
    const float d0 = ptsP[(g * 64 + q8) * 3 + 0] - mx;
    const float d1 = ptsP[(g * 64 + q8) * 3 + 1] - my;
    const float d2 = ptsP[(g * 64 + q8) * 3 + 2] - mz;
    #pragma unroll
    for (int i = 0; i < C / 64; i++) {
      const int c0 = qq * (C / 8) + i * 8;
      float xa[8];
      if constexpr (X16) {
        f16x8 xr = *(const f16x8*)((const f16*)xsrc + (size_t)sx * C + c0);
        #pragma unroll
        for (int j = 0; j < 8; j++) xa[j] = (float)xr[j];
      } else {
        float4 x0 = *(const float4*)((const float*)xsrc + (size_t)sx * C + c0);
        float4 x1 = *(const float4*)((const float*)xsrc + (size_t)sx * C + c0 + 4);
        xa[0] = x0.x; xa[1] = x0.y; xa[2] = x0.z; xa[3] = x0.w;
        xa[4] = x1.x; xa[5] = x1.y; xa[6] = x1.z; xa[7] = x1.w;
      }
      f16x8 hv;
      #pragma unroll
      for (int jj = 0; jj < 8; jj += 4) {
        const float4 w0 = *(const float4*)(Wpos + 0 * C + c0 + jj);
        const float4 w1 = *(const float4*)(Wpos + 1 * C + c0 + jj);
        const float4 w2 = *(const float4*)(Wpos + 2 * C + c0 + jj);
        const float4 bb = *(const float4*)(bpos + c0 + jj);
        hv[jj + 0] = (f16)(xa[jj + 0] * fmaf(d0, w0.x, fmaf(d1, w1.x, fmaf(d2, w2.x, bb.x))));
        hv[jj + 1] = (f16)(xa[jj + 1] * fmaf(d0, w0.y, fmaf(d1, w1.y, fmaf(d2, w2.y, bb.y))));
        hv[jj + 2] = (f16)(xa[jj + 2] * fmaf(d0, w0.z, fmaf(d1, w1.z, fmaf(d2, w2.z, bb.z))));
        hv[jj + 3] = (f16)(xa[jj + 3] * fmaf(d0, w0.w, fmaf(d1, w1.w, fmaf(d2, w2.w, bb.w))));
      }
      *(f16x8*)((char*)bufH + (((q8 * C + c0) * 2) ^ swzb(q8))) = hv;
    }
  }
  __syncthreads();

  // ---- m1: t1[q][c] (wave w: 16-col slice) -> bufT ----
  {
    f32x4 acc[NPWC] = {};
    stage8<C, C, 0>(A1, nullptr, bufH, w, lane, acc);
    const int ct = (w * NPWC) >> 2, qt0 = (w * NPWC) & 3;
    #pragma unroll
    for (int i = 0; i < NPWC; i++) store8<C, false>(bufT, ct, qt0 + i, lane, acc[i]);
  }
  __syncthreads();

  // ---- m3: sc[q][j] (2 tiles/wave) -> scH ----
  {
    f32x4 acc[2] = {};
    stage8<64, C, 1>(nullptr, bufH, bufT, w, lane, acc);
    const int ct = (w * 2) >> 2, qt0 = (w * 2) & 3;
    #pragma unroll
    for (int i = 0; i < 2; i++) store8<64, false>(scH, ct, qt0 + i, lane, acc[i]);
  }
  __syncthreads();

  // ---- softmax rows of sc (8 threads/row, shfl groups of 8) ----
  {
    f16x8 x8 = *(const f16x8*)((const char*)scH + (((q8 * 64 + qq * 8) * 2) ^ swzb(q8)));
    float v[8];
    float mxv = -3.0e38f;
    #pragma unroll
    for (int j = 0; j < 8; j++) {
      v[j] = (float)x8[j];
      mxv = fmaxf(mxv, v[j]);
    }
    mxv = fmaxf(mxv, __shfl_xor(mxv, 1));
    mxv = fmaxf(mxv, __shfl_xor(mxv, 2));
    mxv = fmaxf(mxv, __shfl_xor(mxv, 4));
    float s = 0.f;
    #pragma unroll
    for (int j = 0; j < 8; j++) { v[j] = __expf(v[j] - mxv); s += v[j]; }
    s += __shfl_xor(s, 1);
    s += __shfl_xor(s, 2);
    s += __shfl_xor(s, 4);
    const float inv = 1.f / s;
    f16x8 pk;
    #pragma unroll
    for (int j = 0; j < 8; j++) pk[j] = (f16)(v[j] * inv);
    *(f16x8*)((char*)scH + (((q8 * 64 + qq * 8) * 2) ^ swzb(q8))) = pk;
  }
  __syncthreads();

  // ---- m4: t2[q][c] = sum_j h[j][c] attn[q][j] -> bufT ----
  {
    f32x4 acc[NPWC] = {};
    stage8<C, 64, 2>(nullptr, bufH, scH, w, lane, acc);
    const int ct = (w * NPWC) >> 2, qt0 = (w * NPWC) & 3;
    #pragma unroll
    for (int i = 0; i < NPWC; i++) store8<C, false>(bufT, ct, qt0 + i, lane, acc[i]);
  }
  __syncthreads();

  // ---- m5: o2r[q][c] = relu(...) -> bufH ----
  {
    f32x4 acc[NPWC] = {};
    stage8<C, C, 0>(A2, nullptr, bufT, w, lane, acc);
    const int ct = (w * NPWC) >> 2, qt0 = (w * NPWC) & 3;
    #pragma unroll
    for (int i = 0; i < NPWC; i++) store8<C, true>(bufH, ct, qt0 + i, lane, acc[i]);
  }
  __syncthreads();

  // ---- m6: y[q][o] -> global (M=128: wave w = 16-col slice ot=w) ----
  {
    f32x4 acc[4] = {};
    stage8<128, C, 0>(A3, nullptr, bufH, w, lane, acc);
    #pragma unroll
    for (int i = 0; i < 4; i++) {
      const int qr = lr + i * 16;
      const int o0 = w * 16 + lk * 4;
      const size_t row = SCAT ? (size_t)sDest[qr] : ((size_t)g * 64 + qr);
      if (OUT16) {
        f16x4 v;
        #pragma unroll
        for (int r = 0; r < 4; r++) v[r] = (f16)acc[i][r];
        *(f16x4*)((f16*)outp + row * 128 + o0) = v;
      } else {
        *(f32x4*)((float*)outp + row * 128 + o0) = acc[i];
      }
    }
  }
}

// ======================= host =======================
extern "C" void kernel_launch(void* const* d_in, const int* in_sizes, int n_in,
                              void* d_out, int out_size, void* d_ws, size_t ws_size,
                              hipStream_t stream) {
  const int*   vox_numbs = (const int*)d_in[0];
  const int*   vox_coors = (const int*)d_in[1];
  const float* vox_feats = (const float*)d_in[2];
  const float* pts_coors = (const float*)d_in[3];
  const float* Wpos1 = (const float*)d_in[4];
  const float* bpos1 = (const float*)d_in[5];
  const float* Wq1   = (const float*)d_in[6];
  const float* Wk1   = (const float*)d_in[7];
  const float* Wv1   = (const float*)d_in[8];
  const float* Wo1   = (const float*)d_in[9];
  const float* Wout1 = (const float*)d_in[10];
  const float* Wpos2 = (const float*)d_in[11];
  const float* bpos2 = (const float*)d_in[12];
  const float* Wq2   = (const float*)d_in[13];
  const float* Wk2   = (const float*)d_in[14];
  const float* Wv2   = (const float*)d_in[15];
  const float* Wo2   = (const float*)d_in[16];
  const float* Wout2 = (const float*)d_in[17];

  const int B = in_sizes[0];
  const int n = in_sizes[1] / 4;       // 262144 = 2^18
  const int ngrp = n / 64;

  char* w = (char*)d_ws;
  auto alloc = [&](size_t bytes) {
    char* p = w;
    w += (bytes + 255) & ~(size_t)255;
    return p;
  };
  u64* keys    = (u64*)alloc((size_t)2 * n * 8);   // keys1 | keys2
  int* ind1    = (int*)alloc((size_t)n * 4);
  int* inv2    = (int*)alloc((size_t)n * 4);
  float* pts1p = (float*)alloc((size_t)n * 3 * 4);
  f16* A1a     = (f16*)alloc(64 * 64 * 2);
  f16* A2a     = (f16*)alloc(64 * 64 * 2);
  f16* A3a     = (f16*)alloc(128 * 64 * 2);
  f16* A1b     = (f16*)alloc(128 * 128 * 2);
  f16* A2b     = (f16*)alloc(128 * 128 * 2);
  f16* A3b     = (f16*)alloc(128 * 128 * 2);
  f16* feats1  = (f16*)alloc((size_t)n * 128 * 2);

  float* out_feats = (float*)d_out;
  float* out_pts   = out_feats + (size_t)n * 128;
  float* out_vox   = out_pts + (size_t)n * 3;
  float* out_nb    = out_vox + (size_t)n * 4;

  auto f64k  = block_mfma<64,  false, true,  true,  true>;
  auto f128k = block_mfma<128, true,  false, false, false>;
  hipFuncSetAttribute((const void*)f64k,  hipFuncAttributeMaxDynamicSharedMemorySize, 65536);
  hipFuncSetAttribute((const void*)f128k, hipFuncAttributeMaxDynamicSharedMemorySize, 65536);

  // ---- batch-segmented bitonic sort; prep folded into tile0 launch ----
  int span = (B > 0) ? n / B : n;
  if (span < 4096 || (span & (span - 1)) != 0 || n % span != 0) span = n;
  const int spanm1 = span - 1;
  const int nbsort = 2 * n / 2048;

  sort_tile0_prep<<<nbsort + 16, 1024, 0, stream>>>(
      vox_coors, keys, n, spanm1, nbsort,
      Wq1, Wk1, Wv1, Wo1, Wout1, Wq2, Wk2, Wv2, Wo2, Wout2,
      A1a, A2a, A3a, A1b, A2b, A3b);

  for (int k = 4096; k <= span; k <<= 1) {
    int j = k >> 1;
    while (j >= 4096) {
      int lev = 1;
      while (lev < 4 && (j >> lev) >= 4096) lev++;
      const int jlow = j >> (lev - 1);
      const int nth = (2 * n) >> lev;
      bitonic_gN<<<nth / 256, 256, 0, stream>>>(keys, jlow, lev, k, spanm1);
      j = jlow >> 1;
    }
    if (k < span) {
      merge_tile4<<<2 * n / 4096, 1024, 0, stream>>>(keys, k, spanm1);
    } else {
      // final phase: consume sorted tiles directly, keys never written back
      merge_final<<<2 * n / 4096, 1024, 0, stream>>>(
          keys, k, spanm1, n, B, pts_coors, vox_coors, vox_numbs,
          ind1, inv2, pts1p, out_pts, out_vox, out_nb);
    }
  }

  // block1: gather x rows by ind1, scatter output rows to inv2[element]
  block_mfma<64, false, true, true, true><<<ngrp, 512, 24832, stream>>>(
      ind1, inv2, pts1p, vox_feats, Wpos1, bpos1, A1a, A2a, A3a, feats1);
  // block2: fully coalesced x reads (feats1 already in ordering-2)
  block_mfma<128, true, false, false, false><<<ngrp, 512, 40960, stream>>>(
      nullptr, nullptr, out_pts, feats1, Wpos2, bpos2, A1b, A2b, A3b, out_feats);
}

// Round 17
// 260.922 us; speedup vs baseline: 1.1330x; 1.1330x over previous
//
#include <hip/hip_runtime.h>

using u64 = unsigned long long;
typedef _Float16 f16;
using f16x8 = __attribute__((ext_vector_type(8))) _Float16;
using f16x4 = __attribute__((ext_vector_type(4))) _Float16;
using f32x4 = __attribute__((ext_vector_type(4))) float;

// ======================= Hilbert encode (Skilling) =======================
__device__ __forceinline__ int hilbert3(int X0, int X1, int X2) {
  #pragma unroll
  for (int Q = 256; Q > 1; Q >>= 1) {
    const int P = Q - 1;
    if (X0 & Q) X0 ^= P;
    int t1 = (X0 ^ X1) & P;
    if (X1 & Q) X0 ^= P; else { X0 ^= t1; X1 ^= t1; }
    int t2 = (X0 ^ X2) & P;
    if (X2 & Q) X0 ^= P; else { X0 ^= t2; X2 ^= t2; }
  }
  X1 ^= X0;
  X2 ^= X1;
  int t = 0;
  #pragma unroll
  for (int Q = 256; Q > 1; Q >>= 1) if (X2 & Q) t ^= (Q - 1);
  X0 ^= t; X1 ^= t; X2 ^= t;
  int code = 0;
  #pragma unroll
  for (int b = 8; b >= 0; b--)
    code = (code << 3) | (((X0 >> b) & 1) << 2) | (((X1 >> b) & 1) << 1) | ((X2 >> b) & 1);
  return code;
}

__device__ __forceinline__ void cswap(u64& a, u64& b, bool up) {
  if ((a > b) == up) { u64 t = a; a = b; b = t; }
}

// ======================= batch-segmented bitonic sort (2048-tiles) ============
__global__ __launch_bounds__(1024) void sort_tile0(const int* __restrict__ vox,
                                                   u64* __restrict__ keys, int n,
                                                   int spanm1) {
  __shared__ u64 s[2048];
  const int base = blockIdx.x * 2048;
  const int bl = base & spanm1;
  #pragma unroll
  for (int m = 0; m < 2; m++) {
    const int e = base + threadIdx.x + m * 1024;
    const int isrc = e & (n - 1);
    const int4 c = ((const int4*)vox)[isrc];
    const unsigned code = (e < n) ? (unsigned)hilbert3(c.y, c.z, c.w)
                                  : (unsigned)hilbert3(c.w, c.z, c.y);
    s[threadIdx.x + m * 1024] =
        ((u64)(unsigned)c.x << 45) | ((u64)code << 18) | (unsigned)isrc;
  }
  __syncthreads();
  for (int k = 2; k <= 2048; k <<= 1) {
    for (int j = k >> 1; j >= 1; j >>= 1) {
      const int p = threadIdx.x;
      const int i = ((p & ~(j - 1)) << 1) | (p & (j - 1));
      const bool up = (((bl + i) & k) == 0);
      u64 a = s[i], b = s[i | j];
      if ((a > b) == up) { s[i] = b; s[i | j] = a; }
      __syncthreads();
    }
  }
  keys[base + threadIdx.x]        = s[threadIdx.x];
  keys[base + threadIdx.x + 1024] = s[threadIdx.x + 1024];
}

template<int LEV>
__device__ __forceinline__ void gstepT(u64* __restrict__ keys, int t, int jlow,
                                       int k, int spanm1) {
  constexpr int S = 1 << LEV;
  const int i0 = ((t & ~(jlow - 1)) << LEV) | (t & (jlow - 1));
  const bool up = (((i0 & spanm1) & k) == 0);
  u64 x[S];
  #pragma unroll
  for (int m = 0; m < S; m++) x[m] = keys[i0 + (size_t)m * jlow];
  #pragma unroll
  for (int d = S >> 1; d >= 1; d >>= 1)
    #pragma unroll
    for (int m = 0; m < S; m++)
      if (!(m & d)) cswap(x[m], x[m | d], up);
  #pragma unroll
  for (int m = 0; m < S; m++) keys[i0 + (size_t)m * jlow] = x[m];
}

__global__ void bitonic_gN(u64* __restrict__ keys, int jlow, int lev, int k, int spanm1) {
  const int t = blockIdx.x * blockDim.x + threadIdx.x;
  switch (lev) {
    case 1: gstepT<1>(keys, t, jlow, k, spanm1); break;
    case 2: gstepT<2>(keys, t, jlow, k, spanm1); break;
    case 3: gstepT<3>(keys, t, jlow, k, spanm1); break;
    default: gstepT<4>(keys, t, jlow, k, spanm1); break;
  }
}

__global__ __launch_bounds__(1024) void merge_tile2(u64* __restrict__ keys, int k,
                                                    int spanm1) {
  __shared__ u64 s[2048];
  const int base = blockIdx.x * 2048;
  s[threadIdx.x]        = keys[base + threadIdx.x];
  s[threadIdx.x + 1024] = keys[base + threadIdx.x + 1024];
  __syncthreads();
  const bool up = (((base & spanm1) & k) == 0);  // k >= 4096 > tile => uniform
  for (int j = 1024; j >= 1; j >>= 1) {
    const int p = threadIdx.x;
    const int i = ((p & ~(j - 1)) << 1) | (p & (j - 1));
    u64 a = s[i], b = s[i | j];
    if ((a > b) == up) { s[i] = b; s[i | j] = a; }
    __syncthreads();
  }
  keys[base + threadIdx.x]        = s[threadIdx.x];
  keys[base + threadIdx.x + 1024] = s[threadIdx.x + 1024];
}

// ==== permutation extraction ====
__global__ void extract_inv_k(const u64* __restrict__ keys, const float* __restrict__ pts,
                              int* __restrict__ ind, int* __restrict__ inv,
                              float* __restrict__ pts1p, int n) {
  int t = blockIdx.x * blockDim.x + threadIdx.x;
  if (t >= n) return;
  int s = (int)(keys[t] & 0x3FFFFULL);
  ind[t] = s;
  inv[s] = t;
  pts1p[t * 3 + 0] = pts[s * 3 + 0];
  pts1p[t * 3 + 1] = pts[s * 3 + 1];
  pts1p[t * 3 + 2] = pts[s * 3 + 2];
}

__global__ void finish_k(const u64* __restrict__ keys2, const int* __restrict__ inv1,
                         int* __restrict__ g2, const float* __restrict__ pts,
                         const int* __restrict__ vox, const int* __restrict__ numbs,
                         float* __restrict__ out_pts, float* __restrict__ out_vox,
                         float* __restrict__ out_nb, int n, int B) {
  int t = blockIdx.x * blockDim.x + threadIdx.x;
  if (t >= n) return;
  int s = (int)(keys2[t] & 0x3FFFFULL);
  g2[t] = inv1[s];
  out_pts[t * 3 + 0] = pts[s * 3 + 0];
  out_pts[t * 3 + 1] = pts[s * 3 + 1];
  out_pts[t * 3 + 2] = pts[s * 3 + 2];
  const int4 v = ((const int4*)vox)[s];
  out_vox[t * 4 + 0] = (float)v.x;
  out_vox[t * 4 + 1] = (float)v.y;
  out_vox[t * 4 + 2] = (float)v.z;
  out_vox[t * 4 + 3] = (float)v.w;
  if (t < B) out_nb[t] = (float)numbs[t];
}

// ======================= weight folding (f16, transposed) =======================
__global__ void prep_all(const float* __restrict__ Wq1, const float* __restrict__ Wk1,
                         const float* __restrict__ Wv1, const float* __restrict__ Wo1,
                         const float* __restrict__ Wout1,
                         const float* __restrict__ Wq2, const float* __restrict__ Wk2,
                         const float* __restrict__ Wv2, const float* __restrict__ Wo2,
                         const float* __restrict__ Wout2,
                         f16* __restrict__ A1a, f16* __restrict__ A2a, f16* __restrict__ A3a,
                         f16* __restrict__ A1b, f16* __restrict__ A2b, f16* __restrict__ A3b) {
  const int idx = blockIdx.x * blockDim.x + threadIdx.x;   // 16384 threads
  if (idx < 4096) {
    const int a = idx >> 6, b = idx & 63;
    float s1 = 0.f, s2 = 0.f;
    for (int c = 0; c < 64; c++) {
      s1 = fmaf(Wq1[b * 64 + c], Wk1[a * 64 + c], s1);
      s2 = fmaf(Wv1[b * 64 + c], Wo1[c * 64 + a], s2);
    }
    A1a[idx] = (f16)(s1 * 0.125f);
    A2a[idx] = (f16)s2;
  }
  if (idx < 8192) {
    const int o = idx >> 6, c = idx & 63;
    A3a[idx] = (f16)Wout1[c * 128 + o];
  }
  {
    const int a = idx >> 7, b = idx & 127;
    float s1 = 0.f, s2 = 0.f;
    for (int c = 0; c < 128; c++) {
      s1 = fmaf(Wq2[b * 128 + c], Wk2[a * 128 + c], s1);
      s2 = fmaf(Wv2[b * 128 + c], Wo2[c * 128 + a], s2);
    }
    A1b[idx] = (f16)(s1 * 0.08838834764831845f);
    A2b[idx] = (f16)s2;
    A3b[idx] = (f16)Wout2[b * 128 + a];
  }
}

// ======================= MFMA attention block (8-wave fine partition) =========
__device__ __forceinline__ int swzb(int row) {
  return (((row & 7) ^ (((row >> 3) & 3) << 1)) << 4);
}

template<int M, int K, int AMODE>
__device__ __forceinline__ void stage8(const f16* __restrict__ Ag,
                                       const f16* __restrict__ lA,
                                       const f16* __restrict__ lB,
                                       int w, int lane,
                                       f32x4 (&acc)[(M / 16) * 4 / 8]) {
  constexpr int NPW = (M / 16) * 4 / 8;
  constexpr int KT = K / 32;
  const int lr = lane & 15, lk = lane >> 4;
  const int ct = (w * NPW) >> 2;
  const int qt0 = (w * NPW) & 3;
  const int c = ct * 16 + lr;
  f16x8 Af[KT];
  #pragma unroll
  for (int kt = 0; kt < KT; kt++) {
    const int k0 = kt * 32 + lk * 8;
    if (AMODE == 0) {
      Af[kt] = *(const f16x8*)(Ag + (size_t)c * K + k0);
    } else if (AMODE == 1) {
      Af[kt] = *(const f16x8*)((const char*)lA + (((c * K + k0) * 2) ^ swzb(c)));
    } else {
      f16x8 a;
      #pragma unroll
      for (int e = 0; e < 8; e++) {
        const int j = k0 + e;
        a[e] = *(const f16*)((const char*)lA + (((j * M + c) * 2) ^ swzb(j)));
      }
      Af[kt] = a;
    }
  }
  #pragma unroll
  for (int i = 0; i < NPW; i++) {
    const int q = lr + (qt0 + i) * 16;
    #pragma unroll
    for (int kt = 0; kt < KT; kt++) {
      const int k0 = kt * 32 + lk * 8;
      const f16x8 Bf = *(const f16x8*)((const char*)lB + (((q * K + k0) * 2) ^ swzb(q)));
      acc[i] = __builtin_amdgcn_mfma_f32_16x16x32_f16(Af[kt], Bf, acc[i], 0, 0, 0);
    }
  }
}

template<int RL, bool RELU>
__device__ __forceinline__ void store8(f16* __restrict__ dst, int ct, int qt,
                                       int lane, f32x4 v) {
  const int lr = lane & 15, lk = lane >> 4;
  const int q = lr + qt * 16;
  const int c0 = ct * 16 + lk * 4;
  f16x4 o;
  #pragma unroll
  for (int r = 0; r < 4; r++) {
    float x = v[r];
    if (RELU) x = fmaxf(x, 0.f);
    o[r] = (f16)x;
  }
  *(f16x4*)((char*)dst + (((q * RL + c0) * 2) ^ swzb(q))) = o;
}

template<int C, bool X16, bool OUT16>
__global__ __launch_bounds__(512, 8) void block_mfma(
    const int* __restrict__ idx_x, const float* __restrict__ ptsP,
    const void* __restrict__ xsrc,
    const float* __restrict__ Wpos, const float* __restrict__ bpos,
    const f16* __restrict__ A1, const f16* __restrict__ A2, const f16* __restrict__ A3,
    void* __restrict__ outp) {
  constexpr int NPWC = C / 32;             // tiles/wave for M=C stages
  extern __shared__ char smem[];
  f16* bufH = (f16*)smem;            // [64][C] h -> later o2r
  f16* bufT = bufH + 64 * C;         // [64][C] t1 -> later t2
  f16* scH  = bufT + 64 * C;         // [64][64] f16 scores -> attn

  const int g = blockIdx.x;
  const int t = threadIdx.x;
  const int lane = t & 63;
  const int w = t >> 6;
  const int lr = lane & 15, lk = lane >> 4;
  const int q8 = t >> 3, qq = t & 7;       // h-build / softmax: 8 threads per row

  // ---- h = x * ((p-mean)@Wpos + bpos) -> bufH ----
  {
    const int sx = idx_x[g * 64 + q8];
    float mx = ptsP[(g * 64 + lane) * 3 + 0];
    float my = ptsP[(g * 64 + lane) * 3 + 1];
    float mz = ptsP[(g * 64 + lane) * 3 + 2];
    #pragma unroll
    for (int o = 32; o > 0; o >>= 1) {
      mx += __shfl_xor(mx, o); my += __shfl_xor(my, o); mz += __shfl_xor(mz, o);
    }
    mx *= (1.f / 64.f); my *= (1.f / 64.f); mz *= (1.f / 64.f);
    const float d0 = ptsP[(g * 64 + q8) * 3 + 0] - mx;
    const float d1 = ptsP[(g * 64 + q8) * 3 + 1] - my;
    const float d2 = ptsP[(g * 64 + q8) * 3 + 2] - mz;
    #pragma unroll
    for (int i = 0; i < C / 64; i++) {
      const int c0 = qq * (C / 8) + i * 8;
      float xa[8];
      if constexpr (X16) {
        f16x8 xr = *(const f16x8*)((const f16*)xsrc + (size_t)sx * C + c0);
        #pragma unroll
        for (int j = 0; j < 8; j++) xa[j] = (float)xr[j];
      } else {
        float4 x0 = *(const float4*)((const float*)xsrc + (size_t)sx * C + c0);
        float4 x1 = *(const float4*)((const float*)xsrc + (size_t)sx * C + c0 + 4);
        xa[0] = x0.x; xa[1] = x0.y; xa[2] = x0.z; xa[3] = x0.w;
        xa[4] = x1.x; xa[5] = x1.y; xa[6] = x1.z; xa[7] = x1.w;
      }
      f16x8 hv;
      #pragma unroll
      for (int jj = 0; jj < 8; jj += 4) {
        const float4 w0 = *(const float4*)(Wpos + 0 * C + c0 + jj);
        const float4 w1 = *(const float4*)(Wpos + 1 * C + c0 + jj);
        const float4 w2 = *(const float4*)(Wpos + 2 * C + c0 + jj);
        const float4 bb = *(const float4*)(bpos + c0 + jj);
        hv[jj + 0] = (f16)(xa[jj + 0] * fmaf(d0, w0.x, fmaf(d1, w1.x, fmaf(d2, w2.x, bb.x))));
        hv[jj + 1] = (f16)(xa[jj + 1] * fmaf(d0, w0.y, fmaf(d1, w1.y, fmaf(d2, w2.y, bb.y))));
        hv[jj + 2] = (f16)(xa[jj + 2] * fmaf(d0, w0.z, fmaf(d1, w1.z, fmaf(d2, w2.z, bb.z))));
        hv[jj + 3] = (f16)(xa[jj + 3] * fmaf(d0, w0.w, fmaf(d1, w1.w, fmaf(d2, w2.w, bb.w))));
      }
      *(f16x8*)((char*)bufH + (((q8 * C + c0) * 2) ^ swzb(q8))) = hv;
    }
  }
  __syncthreads();

  // ---- m1: t1[q][c] (wave w: 16-col slice) -> bufT ----
  {
    f32x4 acc[NPWC] = {};
    stage8<C, C, 0>(A1, nullptr, bufH, w, lane, acc);
    const int ct = (w * NPWC) >> 2, qt0 = (w * NPWC) & 3;
    #pragma unroll
    for (int i = 0; i < NPWC; i++) store8<C, false>(bufT, ct, qt0 + i, lane, acc[i]);
  }
  __syncthreads();

  // ---- m3: sc[q][j] (2 tiles/wave) -> scH ----
  {
    f32x4 acc[2] = {};
    stage8<64, C, 1>(nullptr, bufH, bufT, w, lane, acc);
    const int ct = (w * 2) >> 2, qt0 = (w * 2) & 3;
    #pragma unroll
    for (int i = 0; i < 2; i++) store8<64, false>(scH, ct, qt0 + i, lane, acc[i]);
  }
  __syncthreads();

  // ---- softmax rows of sc (8 threads/row, shfl groups of 8) ----
  {
    f16x8 x8 = *(const f16x8*)((const char*)scH + (((q8 * 64 + qq * 8) * 2) ^ swzb(q8)));
    float v[8];
    float mxv = -3.0e38f;
    #pragma unroll
    for (int j = 0; j < 8; j++) {
      v[j] = (float)x8[j];
      mxv = fmaxf(mxv, v[j]);
    }
    mxv = fmaxf(mxv, __shfl_xor(mxv, 1));
    mxv = fmaxf(mxv, __shfl_xor(mxv, 2));
    mxv = fmaxf(mxv, __shfl_xor(mxv, 4));
    float s = 0.f;
    #pragma unroll
    for (int j = 0; j < 8; j++) { v[j] = __expf(v[j] - mxv); s += v[j]; }
    s += __shfl_xor(s, 1);
    s += __shfl_xor(s, 2);
    s += __shfl_xor(s, 4);
    const float inv = 1.f / s;
    f16x8 pk;
    #pragma unroll
    for (int j = 0; j < 8; j++) pk[j] = (f16)(v[j] * inv);
    *(f16x8*)((char*)scH + (((q8 * 64 + qq * 8) * 2) ^ swzb(q8))) = pk;
  }
  __syncthreads();

  // ---- m4: t2[q][c] = sum_j h[j][c] attn[q][j] -> bufT ----
  {
    f32x4 acc[NPWC] = {};
    stage8<C, 64, 2>(nullptr, bufH, scH, w, lane, acc);
    const int ct = (w * NPWC) >> 2, qt0 = (w * NPWC) & 3;
    #pragma unroll
    for (int i = 0; i < NPWC; i++) store8<C, false>(bufT, ct, qt0 + i, lane, acc[i]);
  }
  __syncthreads();

  // ---- m5: o2r[q][c] = relu(...) -> bufH ----
  {
    f32x4 acc[NPWC] = {};
    stage8<C, C, 0>(A2, nullptr, bufT, w, lane, acc);
    const int ct = (w * NPWC) >> 2, qt0 = (w * NPWC) & 3;
    #pragma unroll
    for (int i = 0; i < NPWC; i++) store8<C, true>(bufH, ct, qt0 + i, lane, acc[i]);
  }
  __syncthreads();

  // ---- m6: y[q][o] -> global (M=128: wave w = 16-col slice ot=w) ----
  {
    f32x4 acc[4] = {};
    stage8<128, C, 0>(A3, nullptr, bufH, w, lane, acc);
    #pragma unroll
    for (int i = 0; i < 4; i++) {
      const int qr = lr + i * 16;
      const int o0 = w * 16 + lk * 4;
      const size_t row = (size_t)g * 64 + qr;
      if (OUT16) {
        f16x4 v;
        #pragma unroll
        for (int r = 0; r < 4; r++) v[r] = (f16)acc[i][r];
        *(f16x4*)((f16*)outp + row * 128 + o0) = v;
      } else {
        *(f32x4*)((float*)outp + row * 128 + o0) = acc[i];
      }
    }
  }
}

// ======================= host =======================
extern "C" void kernel_launch(void* const* d_in, const int* in_sizes, int n_in,
                              void* d_out, int out_size, void* d_ws, size_t ws_size,
                              hipStream_t stream) {
  const int*   vox_numbs = (const int*)d_in[0];
  const int*   vox_coors = (const int*)d_in[1];
  const float* vox_feats = (const float*)d_in[2];
  const float* pts_coors = (const float*)d_in[3];
  const float* Wpos1 = (const float*)d_in[4];
  const float* bpos1 = (const float*)d_in[5];
  const float* Wq1   = (const float*)d_in[6];
  const float* Wk1   = (const float*)d_in[7];
  const float* Wv1   = (const float*)d_in[8];
  const float* Wo1   = (const float*)d_in[9];
  const float* Wout1 = (const float*)d_in[10];
  const float* Wpos2 = (const float*)d_in[11];
  const float* bpos2 = (const float*)d_in[12];
  const float* Wq2   = (const float*)d_in[13];
  const float* Wk2   = (const float*)d_in[14];
  const float* Wv2   = (const float*)d_in[15];
  const float* Wo2   = (const float*)d_in[16];
  const float* Wout2 = (const float*)d_in[17];

  const int B = in_sizes[0];
  const int n = in_sizes[1] / 4;       // 262144 = 2^18
  const int ngrp = n / 64;

  char* w = (char*)d_ws;
  auto alloc = [&](size_t bytes) {
    char* p = w;
    w += (bytes + 255) & ~(size_t)255;
    return p;
  };
  u64* keys    = (u64*)alloc((size_t)2 * n * 8);   // keys1 | keys2
  int* ind1    = (int*)alloc((size_t)n * 4);
  int* inv1    = (int*)alloc((size_t)n * 4);
  int* g2      = (int*)alloc((size_t)n * 4);
  float* pts1p = (float*)alloc((size_t)n * 3 * 4);
  f16* A1a     = (f16*)alloc(64 * 64 * 2);
  f16* A2a     = (f16*)alloc(64 * 64 * 2);
  f16* A3a     = (f16*)alloc(128 * 64 * 2);
  f16* A1b     = (f16*)alloc(128 * 128 * 2);
  f16* A2b     = (f16*)alloc(128 * 128 * 2);
  f16* A3b     = (f16*)alloc(128 * 128 * 2);
  f16* feats1  = (f16*)alloc((size_t)n * 128 * 2);
  u64* keys2   = keys + n;

  float* out_feats = (float*)d_out;
  float* out_pts   = out_feats + (size_t)n * 128;
  float* out_vox   = out_pts + (size_t)n * 3;
  float* out_nb    = out_vox + (size_t)n * 4;

  auto f64k  = block_mfma<64,  false, true>;
  auto f128k = block_mfma<128, true,  false>;
  hipFuncSetAttribute((const void*)f64k,  hipFuncAttributeMaxDynamicSharedMemorySize, 65536);
  hipFuncSetAttribute((const void*)f128k, hipFuncAttributeMaxDynamicSharedMemorySize, 65536);

  prep_all<<<64, 256, 0, stream>>>(Wq1, Wk1, Wv1, Wo1, Wout1, Wq2, Wk2, Wv2, Wo2, Wout2,
                                   A1a, A2a, A3a, A1b, A2b, A3b);

  // ---- batch-segmented bitonic sort (2048-tiles, both orderings) ----
  int span = (B > 0) ? n / B : n;
  if (span < 4096 || (span & (span - 1)) != 0 || n % span != 0) span = n;
  const int spanm1 = span - 1;

  sort_tile0<<<2 * n / 2048, 1024, 0, stream>>>(vox_coors, keys, n, spanm1);
  for (int k = 4096; k <= span; k <<= 1) {
    int j = k >> 1;
    while (j >= 2048) {
      int lev = 1;
      while (lev < 4 && (j >> lev) >= 2048) lev++;
      const int jlow = j >> (lev - 1);
      const int nth = (2 * n) >> lev;
      bitonic_gN<<<nth / 256, 256, 0, stream>>>(keys, jlow, lev, k, spanm1);
      j = jlow >> 1;
    }
    merge_tile2<<<2 * n / 2048, 1024, 0, stream>>>(keys, k, spanm1);
  }

  extract_inv_k<<<(n + 255) / 256, 256, 0, stream>>>(keys, pts_coors, ind1, inv1, pts1p, n);
  finish_k<<<(n + 255) / 256, 256, 0, stream>>>(keys2, inv1, g2, pts_coors, vox_coors,
                                                vox_numbs, out_pts, out_vox, out_nb, n, B);

  block_mfma<64, false, true><<<ngrp, 512, 24576, stream>>>(
      ind1, pts1p, vox_feats, Wpos1, bpos1, A1a, A2a, A3a, feats1);
  block_mfma<128, true, false><<<ngrp, 512, 40960, stream>>>(
      g2, out_pts, feats1, Wpos2, bpos2, A1b, A2b, A3b, out_feats);
}